// Round 1
// baseline (966.053 us; speedup 1.0000x reference)
//
#include <hip/hip_runtime.h>

#define HH 64
#define WW 64
#define CIN 256
#define COUT 256
#define NB 2

// ---------------- weight transposes ----------------
// dweights [4][256][256][3][3] -> wT [i][k][c][o]
__global__ __launch_bounds__(256) void transpose_dw(const float* __restrict__ dw,
                                                    float* __restrict__ wT) {
    int idx = blockIdx.x * 256 + threadIdx.x;     // 4*9*256*256 = 2359296
    int o = idx & 255;
    int c = (idx >> 8) & 255;
    int rest = idx >> 16;                         // i*9 + k, 0..35
    int k = rest % 9, i = rest / 9;
    wT[idx] = dw[(((i << 8) + o) * 256 + c) * 9 + k];
}

// oweights [4][18][256][3][3] -> owT [r][k][c][ch]
__global__ __launch_bounds__(256) void transpose_ow(const float* __restrict__ ow,
                                                    float* __restrict__ owT) {
    int idx = blockIdx.x * 256 + threadIdx.x;     // 4*9*256*18 = 165888
    int ch = idx % 18;
    int rest = idx / 18;                          // (r*9+k)*256 + c
    int c = rest & 255;
    int rk = rest >> 8;                           // r*9 + k
    int k = rk % 9, r = rk / 9;
    owT[idx] = ow[((r * 18 + ch) * 256 + c) * 9 + k];
}

// ---------------- offset conv (conv + bias + relu) ----------------
// grid: r(4) * b(2) * y(64) = 512 blocks, 64 threads = x lanes
__global__ __launch_bounds__(64) void offset_conv(const float* __restrict__ x,
                                                  const float* __restrict__ owT,
                                                  const float* __restrict__ ob,
                                                  float* __restrict__ off) {
    int blk = blockIdx.x;
    int r = blk >> 7, b = (blk >> 6) & 1, y = blk & 63;
    int px = threadIdx.x;
    int rate = 6 * (r + 1);

    float acc[18];
#pragma unroll
    for (int ch = 0; ch < 18; ++ch) acc[ch] = ob[r * 18 + ch];

    const float* xb = x + (size_t)b * CIN * HH * WW;
    for (int k = 0; k < 9; ++k) {
        int yy = y + (k / 3 - 1) * rate;
        if (yy < 0 || yy >= HH) continue;
        int xx = px + (k % 3 - 1) * rate;
        bool vx = (unsigned)xx < (unsigned)WW;
        const float* xp = xb + yy * WW + xx;
        const float* wp = owT + ((r * 9 + k) * 256) * 18;
        for (int c = 0; c < 256; ++c) {
            float xv = vx ? xp[(size_t)c * 4096] : 0.f;
            const float* w = wp + c * 18;
#pragma unroll
            for (int ch = 0; ch < 18; ++ch)
                acc[ch] = fmaf(w[ch], xv, acc[ch]);
        }
    }
    float* op = off + ((size_t)(r * 2 + b) * 18) * 4096 + y * 64 + px;
#pragma unroll
    for (int ch = 0; ch < 18; ++ch)
        op[(size_t)ch * 4096] = fmaxf(acc[ch], 0.f);
}

// ---------------- deformable conv ----------------
// grid: i(4) * b(2) * y(64) = 512 blocks, 256 threads
// per block: all 256 out-channels x 64 pixels (one row)
__global__ __launch_bounds__(256) void deform_conv(const float* __restrict__ x,
                                                   const float* __restrict__ wT,
                                                   const float* __restrict__ off,
                                                   float* __restrict__ out) {
    int blk = blockIdx.x;
    int i = blk >> 7, b = (blk >> 6) & 1, y = blk & 63;
    int r = (i + 3) & 3;          // (i-1) % 4
    int rate = 6 * (i + 1);
    int tid = threadIdx.x;
    int to = tid & 31, tp = tid >> 5;   // o tile (32), pixel tile (8)

    __shared__ float s_s[8][64];
    __shared__ float s_w[8][256];
    __shared__ int   s_y0[64], s_x0[64];
    __shared__ float s_wy[64], s_wx[64];
    __shared__ float s_out[32][65];

    float acc[8][8];
#pragma unroll
    for (int a = 0; a < 8; ++a)
#pragma unroll
        for (int p = 0; p < 8; ++p) acc[a][p] = 0.f;

    const float* xb = x + (size_t)b * CIN * 4096;
    const float* offb = off + ((size_t)(r * 2 + b) * 18) * 4096 + y * 64;

    for (int k = 0; k < 9; ++k) {
        if (tid < 64) {
            int p = tid;
            float dy = offb[(size_t)(2 * k) * 4096 + p];
            float dx = offb[(size_t)(2 * k + 1) * 4096 + p];
            float py = (float)(y + (k / 3 - 1) * rate) + dy;
            float pxx = (float)(p + (k % 3 - 1) * rate) + dx;
            float fy = floorf(py), fx = floorf(pxx);
            s_y0[p] = (int)fy;
            s_x0[p] = (int)fx;
            s_wy[p] = py - fy;
            s_wx[p] = pxx - fx;
        }
        __syncthreads();
        const float* wk = wT + (((size_t)i * 9 + k) << 16);
        for (int c0 = 0; c0 < 256; c0 += 8) {
            {   // stage 8x64 bilinear samples (2 per thread)
                int p = tid & 63;
                int ccb = tid >> 6;
                int y0 = s_y0[p], x0 = s_x0[p];
                float wy = s_wy[p], wx = s_wx[p];
                bool vy0 = (unsigned)y0 < 64u, vy1 = (unsigned)(y0 + 1) < 64u;
                bool vx0 = (unsigned)x0 < 64u, vx1 = (unsigned)(x0 + 1) < 64u;
                float w00 = (1.f - wy) * (1.f - wx), w01 = (1.f - wy) * wx;
                float w10 = wy * (1.f - wx),         w11 = wy * wx;
                long pix = (long)y0 * 64 + x0;
#pragma unroll
                for (int u = 0; u < 2; ++u) {
                    int cc = ccb + u * 4;
                    const float* xc = xb + (size_t)(c0 + cc) * 4096;
                    float v00 = (vy0 && vx0) ? xc[pix] : 0.f;
                    float v01 = (vy0 && vx1) ? xc[pix + 1] : 0.f;
                    float v10 = (vy1 && vx0) ? xc[pix + 64] : 0.f;
                    float v11 = (vy1 && vx1) ? xc[pix + 65] : 0.f;
                    s_s[cc][p] = v00 * w00 + v01 * w01 + v10 * w10 + v11 * w11;
                }
            }
            {   // stage 8x256 weights, contiguous copy
                const float* wsrc = wk + (c0 << 8);
#pragma unroll
                for (int u = 0; u < 8; ++u)
                    ((float*)s_w)[tid + u * 256] = wsrc[tid + u * 256];
            }
            __syncthreads();
#pragma unroll
            for (int cc = 0; cc < 8; ++cc) {
                float4 w0 = *(const float4*)&s_w[cc][to * 8];
                float4 w1 = *(const float4*)&s_w[cc][to * 8 + 4];
                float4 sa = *(const float4*)&s_s[cc][tp * 8];
                float4 sb = *(const float4*)&s_s[cc][tp * 8 + 4];
                float wv[8] = {w0.x, w0.y, w0.z, w0.w, w1.x, w1.y, w1.z, w1.w};
                float sv[8] = {sa.x, sa.y, sa.z, sa.w, sb.x, sb.y, sb.z, sb.w};
#pragma unroll
                for (int oi = 0; oi < 8; ++oi)
#pragma unroll
                    for (int pi = 0; pi < 8; ++pi)
                        acc[oi][pi] = fmaf(wv[oi], sv[pi], acc[oi][pi]);
            }
            __syncthreads();
        }
    }

    // epilogue: coalesce writes through LDS, 32 o-rows per slab
    for (int og = 0; og < 8; ++og) {
        if ((to >> 2) == og) {
            int tl = (to & 3) * 8;
#pragma unroll
            for (int oi = 0; oi < 8; ++oi)
#pragma unroll
                for (int pi = 0; pi < 8; ++pi)
                    s_out[tl + oi][tp * 8 + pi] = acc[oi][pi];
        }
        __syncthreads();
        int obase = i * COUT + og * 32;
#pragma unroll
        for (int u = 0; u < 8; ++u) {
            int idx = tid + u * 256;         // 0..2047
            int ol = idx >> 6, p = idx & 63;
            out[(((size_t)b * 1024 + obase + ol) * HH + y) * WW + p] = s_out[ol][p];
        }
        __syncthreads();
    }
}

extern "C" void kernel_launch(void* const* d_in, const int* in_sizes, int n_in,
                              void* d_out, int out_size, void* d_ws, size_t ws_size,
                              hipStream_t stream) {
    const float* x  = (const float*)d_in[0];   // [2,256,64,64]
    const float* dw = (const float*)d_in[1];   // [4,256,256,3,3]
    const float* ow = (const float*)d_in[2];   // [4,18,256,3,3]
    const float* ob = (const float*)d_in[3];   // [4,18]
    float* out = (float*)d_out;                // [2,1024,64,64]

    float* ws  = (float*)d_ws;
    float* off = ws;                           // 4*2*18*4096   = 589824
    float* wT  = ws + 589824;                  // 4*9*256*256   = 2359296
    float* owT = ws + 589824 + 2359296;        // 4*9*256*18    = 165888

    transpose_dw<<<2359296 / 256, 256, 0, stream>>>(dw, wT);
    transpose_ow<<<165888 / 256, 256, 0, stream>>>(ow, owT);
    offset_conv<<<512, 64, 0, stream>>>(x, owT, ob, off);
    deform_conv<<<512, 256, 0, stream>>>(x, wT, off, out);
}

// Round 3
// 469.415 us; speedup vs baseline: 2.0580x; 2.0580x over previous
//
#include <hip/hip_runtime.h>
#include <hip/hip_bf16.h>

typedef __attribute__((ext_vector_type(8))) short bf16x8;
typedef __attribute__((ext_vector_type(4))) float f32x4;

// ---------------- weight transposes ----------------
// dweights [4][256][256][3][3] fp32 -> wTb [i][k][o][c] bf16
__global__ __launch_bounds__(256) void transpose_dw_bf16(const float* __restrict__ dw,
                                                         __hip_bfloat16* __restrict__ wTb) {
    int idx = blockIdx.x * 256 + threadIdx.x;      // 4*9*256*256 = 2359296
    int c = idx & 255;
    int o = (idx >> 8) & 255;
    int rest = idx >> 16;                          // i*9 + k
    int k = rest % 9, i = rest / 9;
    wTb[idx] = __float2bfloat16(dw[(((i << 8) + o) * 256 + c) * 9 + k]);
}

// oweights [4][18][256][3][3] -> owT [r][k][c][ch] fp32
__global__ __launch_bounds__(256) void transpose_ow(const float* __restrict__ ow,
                                                    float* __restrict__ owT) {
    int idx = blockIdx.x * 256 + threadIdx.x;      // 4*9*256*18 = 165888
    int ch = idx % 18;
    int rest = idx / 18;
    int c = rest & 255;
    int rk = rest >> 8;
    int k = rk % 9, r = rk / 9;
    owT[idx] = ow[((r * 18 + ch) * 256 + c) * 9 + k];
}

// ---------------- offset conv (round-1 verified version) ----------------
// grid: r(4) * b(2) * y(64) = 512 blocks, 64 threads = x lanes
__global__ __launch_bounds__(64) void offset_conv(const float* __restrict__ x,
                                                  const float* __restrict__ owT,
                                                  const float* __restrict__ ob,
                                                  float* __restrict__ off) {
    int blk = blockIdx.x;
    int r = blk >> 7, b = (blk >> 6) & 1, y = blk & 63;
    int px = threadIdx.x;
    int rate = 6 * (r + 1);

    float acc[18];
#pragma unroll
    for (int ch = 0; ch < 18; ++ch) acc[ch] = ob[r * 18 + ch];

    const float* xb = x + (size_t)b * 256 * 4096;
    for (int k = 0; k < 9; ++k) {
        int yy = y + (k / 3 - 1) * rate;
        if (yy < 0 || yy >= 64) continue;
        int xx = px + (k % 3 - 1) * rate;
        bool vx = (unsigned)xx < 64u;
        const float* xp = xb + yy * 64 + xx;
        const float* wp = owT + ((size_t)(r * 9 + k) * 256) * 18;
        for (int c = 0; c < 256; ++c) {
            float xv = vx ? xp[(size_t)c * 4096] : 0.f;
            const float* wk = wp + c * 18;
#pragma unroll
            for (int ch = 0; ch < 18; ++ch)
                acc[ch] = fmaf(wk[ch], xv, acc[ch]);
        }
    }
    float* op = off + ((size_t)(r * 2 + b) * 18) * 4096 + y * 64 + px;
#pragma unroll
    for (int ch = 0; ch < 18; ++ch)
        op[(size_t)ch * 4096] = fmaxf(acc[ch], 0.f);
}

// ---------------- deformable conv: synchronous bf16-MFMA implicit GEMM ----------------
// grid: 256 blocks; blk&7 = (i,b), blk>>3 = 128-px tile. 512 threads = 8 waves.
// Per K-step (tap x 32ch): global loads -> barrier -> ds_write -> barrier -> MFMA.
__global__ __launch_bounds__(512) void deform_mfma2(const float* __restrict__ x,
                                                    const __hip_bfloat16* __restrict__ wTb,
                                                    const float* __restrict__ off,
                                                    float* __restrict__ out) {
    __shared__ short  s_a[4][256][8];   // [kg][o][8c]  16 KB
    __shared__ short  s_b[4][128][8];   // [kg][px][8c]  8 KB
    __shared__ int4   s_pix[9][128];
    __shared__ float4 s_wt[9][128];

    const int blk = blockIdx.x;
    const int i = (blk & 7) >> 1, b = blk & 1;
    const int px0 = (blk >> 3) << 7;
    const int r = (i + 3) & 3;             // offsets come from branch (i-1)%4
    const int rate = 6 * (i + 1);

    const int tid = threadIdx.x;
    const int lane = tid & 63;
    const int w = tid >> 6;
    const int wo = w >> 2, wp = w & 3;     // o-half, px-quarter
    const int kg = lane >> 4, lm = lane & 15;
    const int sg = tid >> 7, spx = tid & 127;   // B staging: ch-subgroup, pixel
    const int kgA = tid >> 8, oA = tid & 255;   // A staging: ch-subgroup base, o-row

    const float* xb = x + (size_t)b * 256 * 4096;
    const float* offb = off + (size_t)(r * 2 + b) * 18 * 4096;
    const unsigned short* wib = (const unsigned short*)wTb + (size_t)i * 9 * 65536;

    // ---- precompute bilinear coords/weights for 9 taps x 128 px ----
    for (int e = tid; e < 1152; e += 512) {
        int k = e >> 7, pl = e & 127;
        int pg = px0 + pl;
        int yy = pg >> 6, xc = pg & 63;
        float dy = offb[(size_t)(2 * k) * 4096 + pg];
        float dx = offb[(size_t)(2 * k + 1) * 4096 + pg];
        float py = (float)(yy + (k / 3 - 1) * rate) + dy;
        float pxf = (float)(xc + (k % 3 - 1) * rate) + dx;
        float fy = floorf(py), fx = floorf(pxf);
        int y0 = (int)fy, x0 = (int)fx;
        float wy = py - fy, wx = pxf - fx;
        float vy0 = ((unsigned)y0 < 64u) ? 1.f : 0.f;
        float vy1 = ((unsigned)(y0 + 1) < 64u) ? 1.f : 0.f;
        float vx0 = ((unsigned)x0 < 64u) ? 1.f : 0.f;
        float vx1 = ((unsigned)(x0 + 1) < 64u) ? 1.f : 0.f;
        int cy0 = min(max(y0, 0), 63), cy1 = min(max(y0 + 1, 0), 63);
        int cx0 = min(max(x0, 0), 63), cx1 = min(max(x0 + 1, 0), 63);
        s_pix[k][pl] = make_int4(cy0 * 64 + cx0, cy0 * 64 + cx1,
                                 cy1 * 64 + cx0, cy1 * 64 + cx1);
        s_wt[k][pl] = make_float4(vy0 * vx0 * (1.f - wy) * (1.f - wx),
                                  vy0 * vx1 * (1.f - wy) * wx,
                                  vy1 * vx0 * wy * (1.f - wx),
                                  vy1 * vx1 * wy * wx);
    }
    __syncthreads();

    f32x4 acc[8][2];
#pragma unroll
    for (int mi = 0; mi < 8; ++mi) {
        acc[mi][0] = (f32x4)(0.f);
        acc[mi][1] = (f32x4)(0.f);
    }

    for (int t = 0; t < 72; ++t) {
        const int tap = t >> 3;
        const int c0 = (t & 7) << 5;

        // -- global loads (registers only; no LDS hazard, issued before barrier) --
        const unsigned short* wrow = wib + ((size_t)tap * 256 + oA) * 256 + c0;
        uint4 a0 = *(const uint4*)(wrow + kgA * 8);         // channels c0+kgA*8   ..+8
        uint4 a1 = *(const uint4*)(wrow + (kgA + 2) * 8);   // channels c0+(kgA+2)*8..+8

        int4 p = s_pix[tap][spx];
        float4 q = s_wt[tap][spx];
        const float* xc = xb + (size_t)(c0 + sg * 8) * 4096;
        float sv[8];
#pragma unroll
        for (int j = 0; j < 8; ++j) {
            const float* xcj = xc + (size_t)j * 4096;
            sv[j] = xcj[p.x] * q.x + xcj[p.y] * q.y + xcj[p.z] * q.z + xcj[p.w] * q.w;
        }
        unsigned int pk[4];
#pragma unroll
        for (int h = 0; h < 4; ++h) {
            unsigned int b0 = __float_as_uint(sv[2 * h]);
            unsigned int b1 = __float_as_uint(sv[2 * h + 1]);
            b0 += 0x7fffu + ((b0 >> 16) & 1);              // RNE to bf16
            b1 += 0x7fffu + ((b1 >> 16) & 1);
            pk[h] = (b0 >> 16) | (b1 & 0xffff0000u);
        }

        __syncthreads();   // previous step's LDS reads complete
        *(uint4*)&s_a[kgA][oA][0]     = a0;
        *(uint4*)&s_a[kgA + 2][oA][0] = a1;
        *(uint4*)&s_b[sg][spx][0]     = make_uint4(pk[0], pk[1], pk[2], pk[3]);
        __syncthreads();   // staging visible

        bf16x8 bf0 = *(const bf16x8*)&s_b[kg][wp * 32 + lm][0];
        bf16x8 bf1 = *(const bf16x8*)&s_b[kg][wp * 32 + 16 + lm][0];
#pragma unroll
        for (int mi = 0; mi < 8; ++mi) {
            bf16x8 af = *(const bf16x8*)&s_a[kg][wo * 128 + mi * 16 + lm][0];
            acc[mi][0] = __builtin_amdgcn_mfma_f32_16x16x32_bf16(af, bf0, acc[mi][0], 0, 0, 0);
            acc[mi][1] = __builtin_amdgcn_mfma_f32_16x16x32_bf16(af, bf1, acc[mi][1], 0, 0, 0);
        }
    }

    // epilogue: C/D layout col = lane&15 (px), row = (lane>>4)*4 + reg (o)
    float* ob = out + ((size_t)b * 1024 + i * 256) * 4096;
#pragma unroll
    for (int mi = 0; mi < 8; ++mi) {
        int o = wo * 128 + mi * 16 + kg * 4;
#pragma unroll
        for (int ni = 0; ni < 2; ++ni) {
            int pg = px0 + wp * 32 + ni * 16 + lm;
#pragma unroll
            for (int reg = 0; reg < 4; ++reg)
                ob[(size_t)(o + reg) * 4096 + pg] = acc[mi][ni][reg];
        }
    }
}

extern "C" void kernel_launch(void* const* d_in, const int* in_sizes, int n_in,
                              void* d_out, int out_size, void* d_ws, size_t ws_size,
                              hipStream_t stream) {
    const float* x  = (const float*)d_in[0];   // [2,256,64,64]
    const float* dw = (const float*)d_in[1];   // [4,256,256,3,3]
    const float* ow = (const float*)d_in[2];   // [4,18,256,3,3]
    const float* ob = (const float*)d_in[3];   // [4,18]
    float* out = (float*)d_out;                // [2,1024,64,64]

    float* ws  = (float*)d_ws;
    float* off = ws;                                   // 589824 f32
    float* owT = ws + 589824;                          // 165888 f32
    __hip_bfloat16* wTb = (__hip_bfloat16*)(ws + 589824 + 165888);  // 2359296 bf16

    transpose_dw_bf16<<<9216, 256, 0, stream>>>(dw, wTb);
    transpose_ow<<<648, 256, 0, stream>>>(ow, owT);
    offset_conv<<<512, 64, 0, stream>>>(x, owT, ob, off);
    deform_mfma2<<<256, 512, 0, stream>>>(x, wTb, off, out);
}

// Round 4
// 196.122 us; speedup vs baseline: 4.9258x; 2.3935x over previous
//
#include <hip/hip_runtime.h>
#include <hip/hip_bf16.h>

typedef __attribute__((ext_vector_type(8))) short bf16x8;
typedef __attribute__((ext_vector_type(4))) float f32x4;

__device__ __forceinline__ unsigned int rne_pack(float s0, float s1) {
    unsigned int b0 = __float_as_uint(s0), b1 = __float_as_uint(s1);
    b0 += 0x7fffu + ((b0 >> 16) & 1);
    b1 += 0x7fffu + ((b1 >> 16) & 1);
    return (b0 >> 16) | (b1 & 0xffff0000u);
}

// ---------------- weight transposes ----------------
// dweights [4][256][256][3][3] fp32 -> wTb [i][k][o][c] bf16
__global__ __launch_bounds__(256) void transpose_dw_bf16(const float* __restrict__ dw,
                                                         __hip_bfloat16* __restrict__ wTb) {
    int idx = blockIdx.x * 256 + threadIdx.x;      // 2359296
    int c = idx & 255;
    int o = (idx >> 8) & 255;
    int rest = idx >> 16;                          // i*9 + k
    int k = rest % 9, i = rest / 9;
    wTb[idx] = __float2bfloat16(dw[(((i << 8) + o) * 256 + c) * 9 + k]);
}

// oweights [4][18][256][3][3] fp32 -> owTb [r][k][32][256] bf16 (rows 18..31 zero)
__global__ __launch_bounds__(256) void transpose_ow_bf16(const float* __restrict__ ow,
                                                         __hip_bfloat16* __restrict__ owTb) {
    int idx = blockIdx.x * 256 + threadIdx.x;      // 4*9*32*256 = 294912
    int c = idx & 255;
    int m = (idx >> 8) & 31;
    int rk = idx >> 13;                            // r*9 + k
    int k = rk % 9, r = rk / 9;
    float v = (m < 18) ? ow[((r * 18 + m) * 256 + c) * 9 + k] : 0.f;
    owTb[idx] = __float2bfloat16(v);
}

// ---------------- offset conv as bf16-MFMA implicit GEMM ----------------
// grid: 256 blocks; blk&7 = (r,b), blk>>3 = 128-px tile. 512 threads = 8 waves.
// Tile: M=32 (18 used) x 128 px, K = 9 taps x 256 ch, K-step 32.
__global__ __launch_bounds__(512) void offset_mfma(const float* __restrict__ x,
                                                   const __hip_bfloat16* __restrict__ owTb,
                                                   const float* __restrict__ obias,
                                                   float* __restrict__ off) {
    __shared__ short s_a[4][32][8];     // [kg][m][8c]   2 KB
    __shared__ short s_b[4][128][8];    // [kg][px][8c]  8 KB
    __shared__ int   s_pix[9][128];
    __shared__ float s_msk[9][128];

    const int blk = blockIdx.x;
    const int r = (blk & 7) >> 1, b = blk & 1;
    const int px0 = (blk >> 3) << 7;
    const int rate = 6 * (r + 1);

    const int tid = threadIdx.x;
    const int lane = tid & 63;
    const int w = tid >> 6;                       // wave id = px-block of 16
    const int kg = lane >> 4, lm = lane & 15;
    const int sg = tid >> 7, spx = tid & 127;     // B staging
    const int mA = (tid & 127) >> 2, kgA = tid & 3;  // A staging (tid<128)

    const float* xb = x + (size_t)b * 256 * 4096;
    const unsigned short* wrb = (const unsigned short*)owTb + (size_t)r * 9 * 32 * 256;

    // regular dilated-conv sampling coords (zero padding) for 9 taps x 128 px
    for (int e = tid; e < 1152; e += 512) {
        int k = e >> 7, pl = e & 127;
        int pg = px0 + pl;
        int yy = (pg >> 6) + (k / 3 - 1) * rate;
        int xx = (pg & 63) + (k % 3 - 1) * rate;
        bool v = ((unsigned)yy < 64u) && ((unsigned)xx < 64u);
        int cy = min(max(yy, 0), 63), cx = min(max(xx, 0), 63);
        s_pix[k][pl] = cy * 64 + cx;
        s_msk[k][pl] = v ? 1.f : 0.f;
    }
    __syncthreads();

    f32x4 acc0 = (f32x4)(0.f), acc1 = (f32x4)(0.f);

    for (int t = 0; t < 72; ++t) {
        const int tap = t >> 3;
        const int c0 = (t & 7) << 5;

        uint4 a;
        if (tid < 128)
            a = *(const uint4*)(wrb + ((size_t)tap * 32 + mA) * 256 + c0 + kgA * 8);

        int pix = s_pix[tap][spx];
        float msk = s_msk[tap][spx];
        const float* xc = xb + (size_t)(c0 + sg * 8) * 4096;
        float sv[8];
#pragma unroll
        for (int j = 0; j < 8; ++j)
            sv[j] = xc[(size_t)j * 4096 + pix] * msk;
        uint4 pk = make_uint4(rne_pack(sv[0], sv[1]), rne_pack(sv[2], sv[3]),
                              rne_pack(sv[4], sv[5]), rne_pack(sv[6], sv[7]));

        __syncthreads();
        if (tid < 128) *(uint4*)&s_a[kgA][mA][0] = a;
        *(uint4*)&s_b[sg][spx][0] = pk;
        __syncthreads();

        bf16x8 bf  = *(const bf16x8*)&s_b[kg][w * 16 + lm][0];
        bf16x8 af0 = *(const bf16x8*)&s_a[kg][lm][0];
        bf16x8 af1 = *(const bf16x8*)&s_a[kg][16 + lm][0];
        acc0 = __builtin_amdgcn_mfma_f32_16x16x32_bf16(af0, bf, acc0, 0, 0, 0);
        acc1 = __builtin_amdgcn_mfma_f32_16x16x32_bf16(af1, bf, acc1, 0, 0, 0);
    }

    // C/D: col = lane&15 -> px, row = kg*4 + reg -> m; bias + relu
    const float* bias = obias + r * 18;
    float* ob = off + (size_t)(r * 2 + b) * 18 * 4096;
    int px = px0 + w * 16 + lm;
#pragma unroll
    for (int reg = 0; reg < 4; ++reg) {
        int m = kg * 4 + reg;
        ob[(size_t)m * 4096 + px] = fmaxf(acc0[reg] + bias[m], 0.f);
        int m1 = 16 + m;
        if (m1 < 18)
            ob[(size_t)m1 * 4096 + px] = fmaxf(acc1[reg] + bias[m1], 0.f);
    }
}

// ---------------- deformable conv: synchronous bf16-MFMA implicit GEMM ----------------
// (verbatim from round 3 — verified)
__global__ __launch_bounds__(512) void deform_mfma2(const float* __restrict__ x,
                                                    const __hip_bfloat16* __restrict__ wTb,
                                                    const float* __restrict__ off,
                                                    float* __restrict__ out) {
    __shared__ short  s_a[4][256][8];   // [kg][o][8c]  16 KB
    __shared__ short  s_b[4][128][8];   // [kg][px][8c]  8 KB
    __shared__ int4   s_pix[9][128];
    __shared__ float4 s_wt[9][128];

    const int blk = blockIdx.x;
    const int i = (blk & 7) >> 1, b = blk & 1;
    const int px0 = (blk >> 3) << 7;
    const int r = (i + 3) & 3;             // offsets come from branch (i-1)%4
    const int rate = 6 * (i + 1);

    const int tid = threadIdx.x;
    const int lane = tid & 63;
    const int w = tid >> 6;
    const int wo = w >> 2, wp = w & 3;     // o-half, px-quarter
    const int kg = lane >> 4, lm = lane & 15;
    const int sg = tid >> 7, spx = tid & 127;   // B staging: ch-subgroup, pixel
    const int kgA = tid >> 8, oA = tid & 255;   // A staging

    const float* xb = x + (size_t)b * 256 * 4096;
    const float* offb = off + (size_t)(r * 2 + b) * 18 * 4096;
    const unsigned short* wib = (const unsigned short*)wTb + (size_t)i * 9 * 65536;

    for (int e = tid; e < 1152; e += 512) {
        int k = e >> 7, pl = e & 127;
        int pg = px0 + pl;
        int yy = pg >> 6, xc = pg & 63;
        float dy = offb[(size_t)(2 * k) * 4096 + pg];
        float dx = offb[(size_t)(2 * k + 1) * 4096 + pg];
        float py = (float)(yy + (k / 3 - 1) * rate) + dy;
        float pxf = (float)(xc + (k % 3 - 1) * rate) + dx;
        float fy = floorf(py), fx = floorf(pxf);
        int y0 = (int)fy, x0 = (int)fx;
        float wy = py - fy, wx = pxf - fx;
        float vy0 = ((unsigned)y0 < 64u) ? 1.f : 0.f;
        float vy1 = ((unsigned)(y0 + 1) < 64u) ? 1.f : 0.f;
        float vx0 = ((unsigned)x0 < 64u) ? 1.f : 0.f;
        float vx1 = ((unsigned)(x0 + 1) < 64u) ? 1.f : 0.f;
        int cy0 = min(max(y0, 0), 63), cy1 = min(max(y0 + 1, 0), 63);
        int cx0 = min(max(x0, 0), 63), cx1 = min(max(x0 + 1, 0), 63);
        s_pix[k][pl] = make_int4(cy0 * 64 + cx0, cy0 * 64 + cx1,
                                 cy1 * 64 + cx0, cy1 * 64 + cx1);
        s_wt[k][pl] = make_float4(vy0 * vx0 * (1.f - wy) * (1.f - wx),
                                  vy0 * vx1 * (1.f - wy) * wx,
                                  vy1 * vx0 * wy * (1.f - wx),
                                  vy1 * vx1 * wy * wx);
    }
    __syncthreads();

    f32x4 acc[8][2];
#pragma unroll
    for (int mi = 0; mi < 8; ++mi) {
        acc[mi][0] = (f32x4)(0.f);
        acc[mi][1] = (f32x4)(0.f);
    }

    for (int t = 0; t < 72; ++t) {
        const int tap = t >> 3;
        const int c0 = (t & 7) << 5;

        const unsigned short* wrow = wib + ((size_t)tap * 256 + oA) * 256 + c0;
        uint4 a0 = *(const uint4*)(wrow + kgA * 8);
        uint4 a1 = *(const uint4*)(wrow + (kgA + 2) * 8);

        int4 p = s_pix[tap][spx];
        float4 q = s_wt[tap][spx];
        const float* xc = xb + (size_t)(c0 + sg * 8) * 4096;
        float sv[8];
#pragma unroll
        for (int j = 0; j < 8; ++j) {
            const float* xcj = xc + (size_t)j * 4096;
            sv[j] = xcj[p.x] * q.x + xcj[p.y] * q.y + xcj[p.z] * q.z + xcj[p.w] * q.w;
        }
        uint4 pk = make_uint4(rne_pack(sv[0], sv[1]), rne_pack(sv[2], sv[3]),
                              rne_pack(sv[4], sv[5]), rne_pack(sv[6], sv[7]));

        __syncthreads();
        *(uint4*)&s_a[kgA][oA][0]     = a0;
        *(uint4*)&s_a[kgA + 2][oA][0] = a1;
        *(uint4*)&s_b[sg][spx][0]     = pk;
        __syncthreads();

        bf16x8 bf0 = *(const bf16x8*)&s_b[kg][wp * 32 + lm][0];
        bf16x8 bf1 = *(const bf16x8*)&s_b[kg][wp * 32 + 16 + lm][0];
#pragma unroll
        for (int mi = 0; mi < 8; ++mi) {
            bf16x8 af = *(const bf16x8*)&s_a[kg][wo * 128 + mi * 16 + lm][0];
            acc[mi][0] = __builtin_amdgcn_mfma_f32_16x16x32_bf16(af, bf0, acc[mi][0], 0, 0, 0);
            acc[mi][1] = __builtin_amdgcn_mfma_f32_16x16x32_bf16(af, bf1, acc[mi][1], 0, 0, 0);
        }
    }

    float* ob = out + ((size_t)b * 1024 + i * 256) * 4096;
#pragma unroll
    for (int mi = 0; mi < 8; ++mi) {
        int o = wo * 128 + mi * 16 + kg * 4;
#pragma unroll
        for (int ni = 0; ni < 2; ++ni) {
            int pg = px0 + wp * 32 + ni * 16 + lm;
#pragma unroll
            for (int reg = 0; reg < 4; ++reg)
                ob[(size_t)(o + reg) * 4096 + pg] = acc[mi][ni][reg];
        }
    }
}

extern "C" void kernel_launch(void* const* d_in, const int* in_sizes, int n_in,
                              void* d_out, int out_size, void* d_ws, size_t ws_size,
                              hipStream_t stream) {
    const float* x  = (const float*)d_in[0];   // [2,256,64,64]
    const float* dw = (const float*)d_in[1];   // [4,256,256,3,3]
    const float* ow = (const float*)d_in[2];   // [4,18,256,3,3]
    const float* ob = (const float*)d_in[3];   // [4,18]
    float* out = (float*)d_out;                // [2,1024,64,64]

    float* ws  = (float*)d_ws;
    float* off = ws;                                       // 589824 f32
    __hip_bfloat16* wTb  = (__hip_bfloat16*)(ws + 589824); // 2359296 bf16
    __hip_bfloat16* owTb = wTb + 2359296;                  // 294912 bf16

    transpose_dw_bf16<<<9216, 256, 0, stream>>>(dw, wTb);
    transpose_ow_bf16<<<1152, 256, 0, stream>>>(ow, owTb);
    offset_mfma<<<256, 512, 0, stream>>>(x, owTb, ob, off);
    deform_mfma2<<<256, 512, 0, stream>>>(x, wTb, off, out);
}